// Round 12
// baseline (284.853 us; speedup 1.0000x reference)
//
#include <hip/hip_runtime.h>

#define DD 256
#define HH 512
#define BB 128
#define TS 4096   // floats per tape block (16 KB)

#define WAITVM(N) asm volatile("s_waitcnt vmcnt(" #N ")" ::: "memory")

__device__ __forceinline__ float elu_f(float x) {
    return x > 0.f ? x : (__expf(x) - 1.f);
}
__device__ __forceinline__ float rlf(float v, int l) {
    return __uint_as_float(__builtin_amdgcn_readlane(__float_as_uint(v), (unsigned)l));
}
__device__ __forceinline__ float f4c(const float4& v, int r) {
    return r == 0 ? v.x : r == 1 ? v.y : r == 2 ? v.z : v.w;
}

// Unit slot map: lane L, A-reg r (0..3) <-> h = L+64r  [exception (63,3) -> h=510]
//                lane L, B-reg 4+r     <-> h = 255+L+64r [exception (63,3) -> h=511]
__device__ __forceinline__ int pmap(int h) {
    if (h == 510) return 255;
    if (h == 511) return 511;
    return (h < 255) ? (4 * (h & 63) + (h >> 6))
                     : (256 + 4 * ((h - 255) & 63) + ((h - 255) >> 6));
}
__device__ __forceinline__ int p4map(int j) {      // j in [0,256): column map
    return 4 * (j & 63) + (j >> 6);
}
__device__ __forceinline__ int w1base(int hp) {    // m at +0, l at +512
    return (hp <= 254) ? hp * TS
         : (hp <= 509) ? (hp - 255) * TS + 1024
         : 255 * TS + ((hp == 510) ? 0 : 1024);
}
__device__ __forceinline__ int wobase(int hp) {    // m at +0, l at +256
    return (hp <= 254) ? hp * TS + 3072
         : (hp <= 509) ? (hp - 255) * TS + 3584
         : 255 * TS + ((hp == 510) ? 2048 : 2560);
}

// Tape block i (4096 floats), rows lane-packed [pos = p(h) or p4(j)]:
//  [0/512]    W1T[i]     m/l     [1024/1536] W1T[i+255] m/l
//  [2048/2560] W0T[i]    m/l     [3072/3328] WoT[i]     m/l (256)
//  [3584/3840] WoT[i+255] m/l
// Block 255 = appendix: W1T[510] m/l @0/512, W1T[511] m/l @1024/1536,
//  WoT[510] m/l @2048/2304, WoT[511] m/l @2560/2816.  [3072..4095 unused]
__global__ __launch_bounds__(256) void prep(
    const float* __restrict__ w0m_, const float* __restrict__ w0l_,
    const float* __restrict__ w1m_, const float* __restrict__ w1l_,
    const float* __restrict__ wom_, const float* __restrict__ wol_,
    float* __restrict__ tape)
{
    __shared__ float tm[32][33], tl[32][33];
    const int tx = threadIdx.x & 31, ty = threadIdx.x >> 5;
    const unsigned b = blockIdx.x;

    if (b < 256) {                              // W1: 16 h-tiles x 16 hp-tiles
        const int h0 = (int)(b >> 4) << 5, hp0 = (int)(b & 15) << 5;
        #pragma unroll
        for (int j = 0; j < 4; ++j) {
            int r = ty + 8 * j;
            tm[r][tx] = w1m_[(h0 + r) * HH + hp0 + tx];
            tl[r][tx] = w1l_[(h0 + r) * HH + hp0 + tx];
        }
        __syncthreads();
        #pragma unroll
        for (int j = 0; j < 4; ++j) {
            int hp = hp0 + ty + 8 * j;
            int h  = h0 + tx;
            int dh_h = (h <= 254) ? h + 1 : (h <= 509 ? h - 254 : h - 509);
            int dh_p = (hp <= 254) ? hp + 1 : (hp <= 509 ? hp - 254 : hp - 509);
            float mask = (dh_h >= dh_p) ? 1.f : 0.f;
            int base = w1base(hp), p = pmap(h);
            tape[base + p]       = mask * tm[tx][ty + 8 * j];
            tape[base + 512 + p] = mask * tl[tx][ty + 8 * j];
        }
    } else if (b < 384) {                       // W0: 16 h-tiles x 8 i-tiles
        const int b2 = (int)b - 256;
        const int h0 = (b2 >> 3) << 5, i0 = (b2 & 7) << 5;
        #pragma unroll
        for (int j = 0; j < 4; ++j) {
            int r = ty + 8 * j;
            tm[r][tx] = w0m_[(h0 + r) * DD + i0 + tx];
            tl[r][tx] = w0l_[(h0 + r) * DD + i0 + tx];
        }
        __syncthreads();
        #pragma unroll
        for (int j = 0; j < 4; ++j) {
            int i = i0 + ty + 8 * j;
            int h = h0 + tx;
            int p = pmap(h);
            tape[i * TS + 2048 + p] = tm[tx][ty + 8 * j];
            tape[i * TS + 2560 + p] = tl[tx][ty + 8 * j];
        }
    } else {                                    // Wo: 8 j-tiles x 16 hp-tiles
        const int b3 = (int)b - 384;
        const int j0 = (b3 >> 4) << 5, hp0 = (b3 & 15) << 5;
        #pragma unroll
        for (int j = 0; j < 4; ++j) {
            int r = ty + 8 * j;
            tm[r][tx] = wom_[(j0 + r) * HH + hp0 + tx];
            tl[r][tx] = wol_[(j0 + r) * HH + hp0 + tx];
        }
        __syncthreads();
        #pragma unroll
        for (int j = 0; j < 4; ++j) {
            int hp = hp0 + ty + 8 * j;
            int jj = j0 + tx;
            int base = wobase(hp), p = p4map(jj);
            tape[base + p]       = tm[tx][ty + 8 * j];
            tape[base + 256 + p] = tl[tx][ty + 8 * j];
        }
    }
}

// ================================ main =====================================
struct WSet { float4 w[16]; };

__device__ __forceinline__ void ld_set(WSet& S, const float* __restrict__ g, int lane) {
    const float4* p = (const float4*)g;
    #pragma unroll
    for (int k = 0; k < 16; ++k) S.w[k] = p[64 * k + lane];
}

// w[0..3]=W1T[i] mA,mB,lA,lB  w[4..7]=W1T[i+255] mA,mB,lA,lB
// w[8..11]=W0T[i] mA,mB,lA,lB  w[12..15]=WoT[i]m, WoT[i]l, WoT[i+255]m, WoT[i+255]l
template<int Q, int EX>
__device__ __forceinline__ void stepC(
    int t, int lane, const WSet& S,
    float (&a0m)[8], float (&a0l)[8], float (&a1m)[8], float (&a1l)[8],
    float (&Rm)[4], float (&Rl)[4], float (&yv)[4],
    const float (&xv)[4], const float (&bmv)[4], const float (&blv)[4],
    float& ls_sum,
    const float4& exmA, const float4& exmB, const float4& exlA, const float4& exlB,
    const float4& exwm, const float4& exwl)
{
    float mu = rlf(Rm[Q], t) + rlf(bmv[Q], t);
    float ls = 0.5f * (rlf(Rl[Q], t) + rlf(blv[Q], t));
    ls_sum += ls;
    float v = __fdividef(rlf(xv[Q], t) - mu, __expf(ls) + 1e-12f);
    yv[Q] = (lane == t) ? v : yv[Q];

    #pragma unroll
    for (int r = Q; r < 4; ++r) {
        a0m[r]     += v * f4c(S.w[8], r);
        a0m[4 + r] += v * f4c(S.w[9], r);
        a0l[r]     += v * f4c(S.w[10], r);
        a0l[4 + r] += v * f4c(S.w[11], r);
    }

    float p0m = elu_f(rlf(a0m[Q], t)),     p0l = elu_f(rlf(a0l[Q], t));
    float p1m = elu_f(rlf(a0m[4 + Q], t)), p1l = elu_f(rlf(a0l[4 + Q], t));
    float p2m = 0.f, p2l = 0.f;
    if (EX) {
        p2m = elu_f(rlf(a0m[EX == 1 ? 3 : 7], 63));
        p2l = elu_f(rlf(a0l[EX == 1 ? 3 : 7], 63));
    }

    #pragma unroll
    for (int r = Q; r < 4; ++r) {
        a1m[r]     += f4c(S.w[0], r) * p0m + f4c(S.w[4], r) * p1m;
        a1m[4 + r] += f4c(S.w[1], r) * p0m + f4c(S.w[5], r) * p1m;
        a1l[r]     += f4c(S.w[2], r) * p0l + f4c(S.w[6], r) * p1l;
        a1l[4 + r] += f4c(S.w[3], r) * p0l + f4c(S.w[7], r) * p1l;
    }
    if (EX) {
        #pragma unroll
        for (int r = 0; r < 4; ++r) {
            a1m[r]     += f4c(exmA, r) * p2m;
            a1m[4 + r] += f4c(exmB, r) * p2m;
            a1l[r]     += f4c(exlA, r) * p2l;
            a1l[4 + r] += f4c(exlB, r) * p2l;
        }
    }

    float q0m = elu_f(rlf(a1m[Q], t)),     q0l = elu_f(rlf(a1l[Q], t));
    float q1m = elu_f(rlf(a1m[4 + Q], t)), q1l = elu_f(rlf(a1l[4 + Q], t));
    float q2m = 0.f, q2l = 0.f;
    if (EX) {
        q2m = elu_f(rlf(a1m[EX == 1 ? 3 : 7], 63));
        q2l = elu_f(rlf(a1l[EX == 1 ? 3 : 7], 63));
    }

    #pragma unroll
    for (int r = Q; r < 4; ++r) {
        Rm[r] += f4c(S.w[12], r) * q0m + f4c(S.w[14], r) * q1m;
        Rl[r] += f4c(S.w[13], r) * q0l + f4c(S.w[15], r) * q1l;
    }
    if (EX) {
        #pragma unroll
        for (int r = 0; r < 4; ++r) {
            Rm[r] += f4c(exwm, r) * q2m;
            Rl[r] += f4c(exwl, r) * q2l;
        }
    }
}

__global__ __launch_bounds__(128, 1) void made_main(
    const float* __restrict__ x,
    const float* __restrict__ mu_b0, const float* __restrict__ mu_b1,
    const float* __restrict__ mu_bo,
    const float* __restrict__ lv_b0, const float* __restrict__ lv_b1,
    const float* __restrict__ lv_bo,
    const float* __restrict__ tape,
    float* __restrict__ out)
{
    const int row = blockIdx.x;

    // ===== wave 1: L2 prefetcher — stream the full tape, staggered start =====
    if (threadIdx.x >= 64) {
        const int lane = threadIdx.x - 64;
        const int sg = ((row >> 3) & 15) << 4;     // start group, 16 offsets
        unsigned acc = 0;
        #pragma unroll 1
        for (int k = 0; k < 256; ++k) {
            int g = (sg + k) & 255;
            const uint4* p = (const uint4*)(tape + (size_t)g * TS);
            uint4 v[16];
            #pragma unroll
            for (int j = 0; j < 16; ++j) v[j] = p[64 * j + lane];
            #pragma unroll
            for (int j = 0; j < 16; ++j) acc ^= v[j].x ^ v[j].y ^ v[j].z ^ v[j].w;
        }
        // unprovable-dead sink (target is the unused appendix tail — harmless if hit)
        if (acc == 0xDEADBEEFu) ((unsigned*)tape)[255 * TS + 4000] = acc;
        return;
    }

    // ===== wave 0: main serial loop, distance-3 register pipeline =====
    const int lane = threadIdx.x;

    float a0m[8], a0l[8], a1m[8], a1l[8], Rm[4], Rl[4], yv[4];
    float xv[4], bmv[4], blv[4];
    #pragma unroll
    for (int r = 0; r < 4; ++r) {
        a0m[r]     = mu_b0[lane + 64 * r];
        a0m[4 + r] = mu_b0[255 + lane + 64 * r];
        a0l[r]     = lv_b0[lane + 64 * r];
        a0l[4 + r] = lv_b0[255 + lane + 64 * r];
        a1m[r]     = mu_b1[lane + 64 * r];
        a1m[4 + r] = mu_b1[255 + lane + 64 * r];
        a1l[r]     = lv_b1[lane + 64 * r];
        a1l[4 + r] = lv_b1[255 + lane + 64 * r];
        Rm[r] = 0.f; Rl[r] = 0.f; yv[r] = 0.f;
        xv[r]  = x[row * DD + 64 * r + lane];
        bmv[r] = mu_bo[64 * r + lane];
        blv[r] = lv_bo[64 * r + lane];
    }
    if (lane == 63) {   // (63,3) slots host h=510 (A) and h=511 (B)
        a0m[3] = mu_b0[510]; a0m[7] = mu_b0[511];
        a0l[3] = lv_b0[510]; a0l[7] = lv_b0[511];
        a1m[3] = mu_b1[510]; a1m[7] = mu_b1[511];
        a1l[3] = lv_b1[510]; a1l[7] = lv_b1[511];
    }

    // appendix preloads (dead after steps 0/1)
    const float4* a4 = (const float4*)(tape + 255 * TS);
    float4 e510mA = a4[lane],       e510mB = a4[64 + lane];
    float4 e510lA = a4[128 + lane], e510lB = a4[192 + lane];
    float4 e511mA = a4[256 + lane], e511mB = a4[320 + lane];
    float4 e511lA = a4[384 + lane], e511lB = a4[448 + lane];
    float4 wo510m = a4[512 + lane], wo510l = a4[576 + lane];
    float4 wo511m = a4[640 + lane], wo511l = a4[704 + lane];

    const float4 d4 = make_float4(0.f, 0.f, 0.f, 0.f);

    // drain all init loads so vmcnt counts ONLY tape-group batches from here on
    WAITVM(0);

    WSet G0, G1, G2, G3;
    ld_set(G0, tape + 0 * TS, lane);
    ld_set(G1, tape + 1 * TS, lane);
    ld_set(G2, tape + 2 * TS, lane);
    ld_set(G3, tape + 3 * TS, lane);

    float ls_sum = 0.f;

    // Invariant: every step does WAITVM(48) [completes exactly this step's
    // 16-load batch, leaves 3 batches = 48 in flight], computes, then issues
    // 16 loads for step i+4 into the freed group. Cover = 3 full steps.

    // ---- step 0 (extra h=510) ----
    WAITVM(48);
    stepC<0, 1>(0, lane, G0, a0m, a0l, a1m, a1l, Rm, Rl, yv, xv, bmv, blv, ls_sum,
                e510mA, e510mB, e510lA, e510lB, wo510m, wo510l);
    ld_set(G0, tape + 4 * TS, lane);

    // ---- step 1 (extra h=511) ----
    WAITVM(48);
    stepC<0, 2>(1, lane, G1, a0m, a0l, a1m, a1l, Rm, Rl, yv, xv, bmv, blv, ls_sum,
                e511mA, e511mB, e511lA, e511lB, wo511m, wo511l);
    ld_set(G1, tape + 5 * TS, lane);

    // ---- steps 2,3 ----
    WAITVM(48);
    stepC<0, 0>(2, lane, G2, a0m, a0l, a1m, a1l, Rm, Rl, yv, xv, bmv, blv, ls_sum,
                d4, d4, d4, d4, d4, d4);
    ld_set(G2, tape + 6 * TS, lane);
    WAITVM(48);
    stepC<0, 0>(3, lane, G3, a0m, a0l, a1m, a1l, Rm, Rl, yv, xv, bmv, blv, ls_sum,
                d4, d4, d4, d4, d4, d4);
    ld_set(G3, tape + 7 * TS, lane);

#define ONE_STEP(Q, G, i, t)                                                  \
    {                                                                         \
        int gn = (i) + 4 > 254 ? 254 : (i) + 4;                               \
        WAITVM(48);                                                           \
        stepC<Q, 0>((t), lane, G, a0m, a0l, a1m, a1l, Rm, Rl, yv,             \
                    xv, bmv, blv, ls_sum, d4, d4, d4, d4, d4, d4);            \
        ld_set(G, tape + (size_t)gn * TS, lane);                              \
    }
#define QUAD(Q, i, t)                                                         \
    ONE_STEP(Q, G0, (i),     (t))                                             \
    ONE_STEP(Q, G1, (i) + 1, (t) + 1)                                         \
    ONE_STEP(Q, G2, (i) + 2, (t) + 2)                                         \
    ONE_STEP(Q, G3, (i) + 3, (t) + 3)

    #pragma unroll 1
    for (int i = 4; i < 64; i += 4)    { QUAD(0, i, i) }
    #pragma unroll 1
    for (int i = 64; i < 128; i += 4)  { QUAD(1, i, i - 64) }
    #pragma unroll 1
    for (int i = 128; i < 192; i += 4) { QUAD(2, i, i - 128) }
    #pragma unroll 1
    for (int i = 192; i < 252; i += 4) { QUAD(3, i, i - 192) }

    // ---- steps 252,253,254 (G0,G1,G2) ----
    ONE_STEP(3, G0, 252, 60)
    ONE_STEP(3, G1, 253, 61)
    WAITVM(48);
    stepC<3, 0>(62, lane, G2, a0m, a0l, a1m, a1l, Rm, Rl, yv, xv, bmv, blv, ls_sum,
                d4, d4, d4, d4, d4, d4);
#undef ONE_STEP
#undef QUAD

    // ---- step 255: output only (no weights) ----
    {
        float mu = rlf(Rm[3], 63) + rlf(bmv[3], 63);
        float ls = 0.5f * (rlf(Rl[3], 63) + rlf(blv[3], 63));
        ls_sum += ls;
        float v = __fdividef(rlf(xv[3], 63) - mu, __expf(ls) + 1e-12f);
        yv[3] = (lane == 63) ? v : yv[3];
    }

    #pragma unroll
    for (int r = 0; r < 4; ++r) out[row * DD + 64 * r + lane] = yv[r];
    if (lane == 0) out[BB * DD + row] = ls_sum;
}

extern "C" void kernel_launch(void* const* d_in, const int* in_sizes, int n_in,
                              void* d_out, int out_size, void* d_ws, size_t ws_size,
                              hipStream_t stream) {
    const float* x     = (const float*)d_in[0];
    const float* mu_W0 = (const float*)d_in[1];
    const float* mu_b0 = (const float*)d_in[2];
    const float* mu_W1 = (const float*)d_in[3];
    const float* mu_b1 = (const float*)d_in[4];
    const float* mu_Wo = (const float*)d_in[5];
    const float* mu_bo = (const float*)d_in[6];
    const float* lv_W0 = (const float*)d_in[7];
    const float* lv_b0 = (const float*)d_in[8];
    const float* lv_W1 = (const float*)d_in[9];
    const float* lv_b1 = (const float*)d_in[10];
    const float* lv_Wo = (const float*)d_in[11];
    const float* lv_bo = (const float*)d_in[12];

    float* tape = (float*)d_ws;   // 4 MiB

    prep<<<512, 256, 0, stream>>>(mu_W0, lv_W0, mu_W1, lv_W1, mu_Wo, lv_Wo, tape);
    made_main<<<BB, 128, 0, stream>>>(x, mu_b0, mu_b1, mu_bo,
                                      lv_b0, lv_b1, lv_bo, tape, (float*)d_out);
}

// Round 13
// 225.068 us; speedup vs baseline: 1.2656x; 1.2656x over previous
//
#include <hip/hip_runtime.h>

#define DD 256
#define HH 512
#define BB 128
#define TS 4096   // floats per tape block (16 KB)

#define WAITVM(N) asm volatile("s_waitcnt vmcnt(" #N ")" ::: "memory")

__device__ __forceinline__ float elu_f(float x) {
    return x > 0.f ? x : (__expf(x) - 1.f);
}
__device__ __forceinline__ float rlf(float v, int l) {
    return __uint_as_float(__builtin_amdgcn_readlane(__float_as_uint(v), (unsigned)l));
}
__device__ __forceinline__ float f4c(const float4& v, int r) {
    return r == 0 ? v.x : r == 1 ? v.y : r == 2 ? v.z : v.w;
}

// Unit slot map: lane L, A-reg r (0..3) <-> h = L+64r  [exception (63,3) -> h=510]
//                lane L, B-reg 4+r     <-> h = 255+L+64r [exception (63,3) -> h=511]
__device__ __forceinline__ int pmap(int h) {
    if (h == 510) return 255;
    if (h == 511) return 511;
    return (h < 255) ? (4 * (h & 63) + (h >> 6))
                     : (256 + 4 * ((h - 255) & 63) + ((h - 255) >> 6));
}
__device__ __forceinline__ int p4map(int j) {      // j in [0,256): column map
    return 4 * (j & 63) + (j >> 6);
}
__device__ __forceinline__ int w1base(int hp) {    // m at +0, l at +512
    return (hp <= 254) ? hp * TS
         : (hp <= 509) ? (hp - 255) * TS + 1024
         : 255 * TS + ((hp == 510) ? 0 : 1024);
}
__device__ __forceinline__ int wobase(int hp) {    // m at +0, l at +256
    return (hp <= 254) ? hp * TS + 3072
         : (hp <= 509) ? (hp - 255) * TS + 3584
         : 255 * TS + ((hp == 510) ? 2048 : 2560);
}

// Tape block i (4096 floats), rows lane-packed [pos = p(h) or p4(j)]:
//  [0/512]    W1T[i]     m/l     [1024/1536] W1T[i+255] m/l
//  [2048/2560] W0T[i]    m/l     [3072/3328] WoT[i]     m/l (256)
//  [3584/3840] WoT[i+255] m/l
// Block 255 = appendix: W1T[510] m/l @0/512, W1T[511] m/l @1024/1536,
//  WoT[510] m/l @2048/2304, WoT[511] m/l @2560/2816.  [3072..4095 unused]
__global__ __launch_bounds__(256) void prep(
    const float* __restrict__ w0m_, const float* __restrict__ w0l_,
    const float* __restrict__ w1m_, const float* __restrict__ w1l_,
    const float* __restrict__ wom_, const float* __restrict__ wol_,
    float* __restrict__ tape)
{
    __shared__ float tm[32][33], tl[32][33];
    const int tx = threadIdx.x & 31, ty = threadIdx.x >> 5;
    const unsigned b = blockIdx.x;

    if (b < 256) {                              // W1: 16 h-tiles x 16 hp-tiles
        const int h0 = (int)(b >> 4) << 5, hp0 = (int)(b & 15) << 5;
        #pragma unroll
        for (int j = 0; j < 4; ++j) {
            int r = ty + 8 * j;
            tm[r][tx] = w1m_[(h0 + r) * HH + hp0 + tx];
            tl[r][tx] = w1l_[(h0 + r) * HH + hp0 + tx];
        }
        __syncthreads();
        #pragma unroll
        for (int j = 0; j < 4; ++j) {
            int hp = hp0 + ty + 8 * j;
            int h  = h0 + tx;
            int dh_h = (h <= 254) ? h + 1 : (h <= 509 ? h - 254 : h - 509);
            int dh_p = (hp <= 254) ? hp + 1 : (hp <= 509 ? hp - 254 : hp - 509);
            float mask = (dh_h >= dh_p) ? 1.f : 0.f;
            int base = w1base(hp), p = pmap(h);
            tape[base + p]       = mask * tm[tx][ty + 8 * j];
            tape[base + 512 + p] = mask * tl[tx][ty + 8 * j];
        }
    } else if (b < 384) {                       // W0: 16 h-tiles x 8 i-tiles
        const int b2 = (int)b - 256;
        const int h0 = (b2 >> 3) << 5, i0 = (b2 & 7) << 5;
        #pragma unroll
        for (int j = 0; j < 4; ++j) {
            int r = ty + 8 * j;
            tm[r][tx] = w0m_[(h0 + r) * DD + i0 + tx];
            tl[r][tx] = w0l_[(h0 + r) * DD + i0 + tx];
        }
        __syncthreads();
        #pragma unroll
        for (int j = 0; j < 4; ++j) {
            int i = i0 + ty + 8 * j;
            int h = h0 + tx;
            int p = pmap(h);
            tape[i * TS + 2048 + p] = tm[tx][ty + 8 * j];
            tape[i * TS + 2560 + p] = tl[tx][ty + 8 * j];
        }
    } else {                                    // Wo: 8 j-tiles x 16 hp-tiles
        const int b3 = (int)b - 384;
        const int j0 = (b3 >> 4) << 5, hp0 = (b3 & 15) << 5;
        #pragma unroll
        for (int j = 0; j < 4; ++j) {
            int r = ty + 8 * j;
            tm[r][tx] = wom_[(j0 + r) * HH + hp0 + tx];
            tl[r][tx] = wol_[(j0 + r) * HH + hp0 + tx];
        }
        __syncthreads();
        #pragma unroll
        for (int j = 0; j < 4; ++j) {
            int hp = hp0 + ty + 8 * j;
            int jj = j0 + tx;
            int base = wobase(hp), p = p4map(jj);
            tape[base + p]       = tm[tx][ty + 8 * j];
            tape[base + 256 + p] = tl[tx][ty + 8 * j];
        }
    }
}

// ================================ main =====================================
struct WSet { float4 w[16]; };

__device__ __forceinline__ void ld_set(WSet& S, const float* __restrict__ g, int lane) {
    const float4* p = (const float4*)g;
    #pragma unroll
    for (int k = 0; k < 16; ++k) S.w[k] = p[64 * k + lane];
}

// w[0..3]=W1T[i] mA,mB,lA,lB  w[4..7]=W1T[i+255] mA,mB,lA,lB
// w[8..11]=W0T[i] mA,mB,lA,lB  w[12..15]=WoT[i]m, WoT[i]l, WoT[i+255]m, WoT[i+255]l
// R accumulators are bias-initialized, so mu/ls are direct readlanes.
template<int Q, int EX>
__device__ __forceinline__ void stepC(
    int t, int lane, const WSet& S, float xi,
    float (&a0m)[8], float (&a0l)[8], float (&a1m)[8], float (&a1l)[8],
    float (&Rm)[4], float (&Rl)[4], float (&yv)[4],
    float& ls_sum,
    const float4& exmA, const float4& exmB, const float4& exlA, const float4& exlB,
    const float4& exwm, const float4& exwl)
{
    float mu = rlf(Rm[Q], t);
    float ls = 0.5f * rlf(Rl[Q], t);
    ls_sum += ls;
    float v = __fdividef(xi - mu, __expf(ls) + 1e-12f);
    yv[Q] = (lane == t) ? v : yv[Q];

    #pragma unroll
    for (int r = Q; r < 4; ++r) {
        a0m[r]     += v * f4c(S.w[8], r);
        a0m[4 + r] += v * f4c(S.w[9], r);
        a0l[r]     += v * f4c(S.w[10], r);
        a0l[4 + r] += v * f4c(S.w[11], r);
    }

    float p0m = elu_f(rlf(a0m[Q], t)),     p0l = elu_f(rlf(a0l[Q], t));
    float p1m = elu_f(rlf(a0m[4 + Q], t)), p1l = elu_f(rlf(a0l[4 + Q], t));
    float p2m = 0.f, p2l = 0.f;
    if (EX) {
        p2m = elu_f(rlf(a0m[EX == 1 ? 3 : 7], 63));
        p2l = elu_f(rlf(a0l[EX == 1 ? 3 : 7], 63));
    }

    #pragma unroll
    for (int r = Q; r < 4; ++r) {
        a1m[r]     += f4c(S.w[0], r) * p0m + f4c(S.w[4], r) * p1m;
        a1m[4 + r] += f4c(S.w[1], r) * p0m + f4c(S.w[5], r) * p1m;
        a1l[r]     += f4c(S.w[2], r) * p0l + f4c(S.w[6], r) * p1l;
        a1l[4 + r] += f4c(S.w[3], r) * p0l + f4c(S.w[7], r) * p1l;
    }
    if (EX) {
        #pragma unroll
        for (int r = 0; r < 4; ++r) {
            a1m[r]     += f4c(exmA, r) * p2m;
            a1m[4 + r] += f4c(exmB, r) * p2m;
            a1l[r]     += f4c(exlA, r) * p2l;
            a1l[4 + r] += f4c(exlB, r) * p2l;
        }
    }

    float q0m = elu_f(rlf(a1m[Q], t)),     q0l = elu_f(rlf(a1l[Q], t));
    float q1m = elu_f(rlf(a1m[4 + Q], t)), q1l = elu_f(rlf(a1l[4 + Q], t));
    float q2m = 0.f, q2l = 0.f;
    if (EX) {
        q2m = elu_f(rlf(a1m[EX == 1 ? 3 : 7], 63));
        q2l = elu_f(rlf(a1l[EX == 1 ? 3 : 7], 63));
    }

    #pragma unroll
    for (int r = Q; r < 4; ++r) {
        Rm[r] += f4c(S.w[12], r) * q0m + f4c(S.w[14], r) * q1m;
        Rl[r] += f4c(S.w[13], r) * q0l + f4c(S.w[15], r) * q1l;
    }
    if (EX) {
        #pragma unroll
        for (int r = 0; r < 4; ++r) {
            Rm[r] += f4c(exwm, r) * q2m;
            Rl[r] += f4c(exwl, r) * q2l;
        }
    }
}

__global__ __launch_bounds__(128, 1) void made_main(
    const float* __restrict__ x,
    const float* __restrict__ mu_b0, const float* __restrict__ mu_b1,
    const float* __restrict__ mu_bo,
    const float* __restrict__ lv_b0, const float* __restrict__ lv_b1,
    const float* __restrict__ lv_bo,
    const float* __restrict__ tape,
    float* __restrict__ out)
{
    const int row = blockIdx.x;

    // ===== wave 1: L2 prefetcher — stream the full tape, staggered start =====
    if (threadIdx.x >= 64) {
        const int lane = threadIdx.x - 64;
        const int sg = ((row >> 3) & 15) << 4;     // start group, 16 offsets
        unsigned acc = 0;
        #pragma unroll 1
        for (int k = 0; k < 256; ++k) {
            int g = (sg + k) & 255;
            const uint4* p = (const uint4*)(tape + (size_t)g * TS);
            uint4 v[16];
            #pragma unroll
            for (int j = 0; j < 16; ++j) v[j] = p[64 * j + lane];
            #pragma unroll
            for (int j = 0; j < 16; ++j) acc ^= v[j].x ^ v[j].y ^ v[j].z ^ v[j].w;
        }
        // unprovable-dead sink (target is the unused appendix tail — harmless if hit)
        if (acc == 0xDEADBEEFu) ((unsigned*)tape)[255 * TS + 4000] = acc;
        return;
    }

    // ===== wave 0: main serial loop, 3-group distance-3 register pipeline =====
    const int lane = threadIdx.x;

    float a0m[8], a0l[8], a1m[8], a1l[8], Rm[4], Rl[4], yv[4];
    #pragma unroll
    for (int r = 0; r < 4; ++r) {
        a0m[r]     = mu_b0[lane + 64 * r];
        a0m[4 + r] = mu_b0[255 + lane + 64 * r];
        a0l[r]     = lv_b0[lane + 64 * r];
        a0l[4 + r] = lv_b0[255 + lane + 64 * r];
        a1m[r]     = mu_b1[lane + 64 * r];
        a1m[4 + r] = mu_b1[255 + lane + 64 * r];
        a1l[r]     = lv_b1[lane + 64 * r];
        a1l[4 + r] = lv_b1[255 + lane + 64 * r];
        Rm[r] = mu_bo[64 * r + lane];      // bias-initialized output accumulators
        Rl[r] = lv_bo[64 * r + lane];
        yv[r] = 0.f;
    }
    if (lane == 63) {   // (63,3) slots host h=510 (A) and h=511 (B)
        a0m[3] = mu_b0[510]; a0m[7] = mu_b0[511];
        a0l[3] = lv_b0[510]; a0l[7] = lv_b0[511];
        a1m[3] = mu_b1[510]; a1m[7] = mu_b1[511];
        a1l[3] = lv_b1[510]; a1l[7] = lv_b1[511];
    }

    float ls_sum = 0.f;
    const float4 d4 = make_float4(0.f, 0.f, 0.f, 0.f);

    WSet G0, G1, G2;

    // ---- steps 0/1: un-pipelined, with appendix (regs die before G2 lives) ----
    {
        const float4* a4 = (const float4*)(tape + 255 * TS);
        float4 e510mA = a4[lane],       e510mB = a4[64 + lane];
        float4 e510lA = a4[128 + lane], e510lB = a4[192 + lane];
        float4 e511mA = a4[256 + lane], e511mB = a4[320 + lane];
        float4 e511lA = a4[384 + lane], e511lB = a4[448 + lane];
        float4 wo510m = a4[512 + lane], wo510l = a4[576 + lane];
        float4 wo511m = a4[640 + lane], wo511l = a4[704 + lane];

        ld_set(G0, tape + 0 * TS, lane);
        ld_set(G1, tape + 1 * TS, lane);

        float xi0 = x[row * DD + 0];
        stepC<0, 1>(0, lane, G0, xi0, a0m, a0l, a1m, a1l, Rm, Rl, yv, ls_sum,
                    e510mA, e510mB, e510lA, e510lB, wo510m, wo510l);
        float xi1 = x[row * DD + 1];
        stepC<0, 2>(1, lane, G1, xi1, a0m, a0l, a1m, a1l, Rm, Rl, yv, ls_sum,
                    e511mA, e511mB, e511lA, e511lB, wo511m, wo511l);
    }

    // ---- prime the pipeline: blocks 2,3,4 in flight; clean vmcnt from here ----
    WAITVM(0);
    ld_set(G0, tape + 2 * TS, lane);
    ld_set(G1, tape + 3 * TS, lane);
    ld_set(G2, tape + 4 * TS, lane);

    // Invariant: at step i, outstanding = batches i,i+1,i+2 (48 loads).
    // WAITVM(32) completes batch i, leaves 2 in flight; compute; issue batch i+3.
#define ONE_STEP(Q, G, i, t)                                                  \
    {                                                                         \
        int gn = (i) + 3 > 254 ? 254 : (i) + 3;                               \
        float xi = x[row * DD + (i)];                                         \
        WAITVM(32);                                                           \
        stepC<Q, 0>((t), lane, G, xi, a0m, a0l, a1m, a1l, Rm, Rl, yv,         \
                    ls_sum, d4, d4, d4, d4, d4, d4);                          \
        ld_set(G, tape + (size_t)gn * TS, lane);                              \
    }
#define TRIO_A(Q, i, t) ONE_STEP(Q, G0, (i), (t)) ONE_STEP(Q, G1, (i)+1, (t)+1) ONE_STEP(Q, G2, (i)+2, (t)+2)
#define TRIO_B(Q, i, t) ONE_STEP(Q, G1, (i), (t)) ONE_STEP(Q, G2, (i)+1, (t)+1) ONE_STEP(Q, G0, (i)+2, (t)+2)
#define TRIO_C(Q, i, t) ONE_STEP(Q, G2, (i), (t)) ONE_STEP(Q, G0, (i)+1, (t)+1) ONE_STEP(Q, G1, (i)+2, (t)+2)

    // step i uses G[(i-2) mod 3]; phase boundaries stitched to keep rotation.
    #pragma unroll 1
    for (int i = 2; i < 62; i += 3)    { TRIO_A(0, i, i) }          // 2..61
    ONE_STEP(0, G0, 62, 62)
    ONE_STEP(0, G1, 63, 63)
    #pragma unroll 1
    for (int i = 64; i < 127; i += 3)  { TRIO_C(1, i, i - 64) }     // 64..126
    ONE_STEP(1, G2, 127, 63)
    #pragma unroll 1
    for (int i = 128; i < 191; i += 3) { TRIO_A(2, i, i - 128) }    // 128..190
    ONE_STEP(2, G0, 191, 63)
    #pragma unroll 1
    for (int i = 192; i < 255; i += 3) { TRIO_B(3, i, i - 192) }    // 192..254
#undef ONE_STEP
#undef TRIO_A
#undef TRIO_B
#undef TRIO_C

    // ---- step 255: output only (no weights) ----
    {
        float xi = x[row * DD + 255];
        float mu = rlf(Rm[3], 63);
        float ls = 0.5f * rlf(Rl[3], 63);
        ls_sum += ls;
        float v = __fdividef(xi - mu, __expf(ls) + 1e-12f);
        yv[3] = (lane == 63) ? v : yv[3];
    }

    #pragma unroll
    for (int r = 0; r < 4; ++r) out[row * DD + 64 * r + lane] = yv[r];
    if (lane == 0) out[BB * DD + row] = ls_sum;
}

extern "C" void kernel_launch(void* const* d_in, const int* in_sizes, int n_in,
                              void* d_out, int out_size, void* d_ws, size_t ws_size,
                              hipStream_t stream) {
    const float* x     = (const float*)d_in[0];
    const float* mu_W0 = (const float*)d_in[1];
    const float* mu_b0 = (const float*)d_in[2];
    const float* mu_W1 = (const float*)d_in[3];
    const float* mu_b1 = (const float*)d_in[4];
    const float* mu_Wo = (const float*)d_in[5];
    const float* mu_bo = (const float*)d_in[6];
    const float* lv_W0 = (const float*)d_in[7];
    const float* lv_b0 = (const float*)d_in[8];
    const float* lv_W1 = (const float*)d_in[9];
    const float* lv_b1 = (const float*)d_in[10];
    const float* lv_Wo = (const float*)d_in[11];
    const float* lv_bo = (const float*)d_in[12];

    float* tape = (float*)d_ws;   // 4 MiB

    prep<<<512, 256, 0, stream>>>(mu_W0, lv_W0, mu_W1, lv_W1, mu_Wo, lv_Wo, tape);
    made_main<<<BB, 128, 0, stream>>>(x, mu_b0, mu_b1, mu_bo,
                                      lv_b0, lv_b1, lv_bo, tape, (float*)d_out);
}